// Round 6
// baseline (503.931 us; speedup 1.0000x reference)
//
#include <hip/hip_runtime.h>
#include <hip/hip_bf16.h>
#include <cstddef>

#define NP1 6001
#define BLn 6400
#define TRI 20100   // 200*201/2 causal pairs per batch

__global__ __launch_bounds__(256) void k_mark(const int* logs, int* used) {
    int i = blockIdx.x * 256 + threadIdx.x;
    if (i < BLn) used[logs[i]] = 1;
}

// used=0 init folded in; h_item = item_emb @ W_item ; wh1 = h@a[:64] ; wh2 = h@a[64:]
__global__ __launch_bounds__(256) void k_hitem(const float* emb, const float* Wi,
                                               const float* a_item,
                                               float* h, float* wh1, float* wh2, int* used) {
    __shared__ float Wl[4096];
    int tid = threadIdx.x;
    int gid = blockIdx.x * 256 + tid;
    if (gid < NP1) used[gid] = 0;
    {
        const float4* w4 = (const float4*)Wi;
        float4* l4 = (float4*)Wl;
        for (int i = tid; i < 1024; i += 256) l4[i] = w4[i];
    }
    __syncthreads();
    int wave = tid >> 6, lane = tid & 63;
    int row = blockIdx.x * 4 + wave;
    if (row >= NP1) return;
    float e = emb[(size_t)row * 64 + lane];
    float acc = 0.f;
    #pragma unroll
    for (int k = 0; k < 64; k++) acc += __shfl(e, k, 64) * Wl[k * 64 + lane];
    h[(size_t)row * 64 + lane] = acc;
    float p1 = acc * a_item[lane];
    float p2 = acc * a_item[64 + lane];
    for (int off = 32; off > 0; off >>= 1) {
        p1 += __shfl_down(p1, off, 64);
        p2 += __shfl_down(p2, off, 64);
    }
    if (lane == 0) { wh1[row] = p1; wh2[row] = p2; }
}

#define MAXNZ 1024
// one block per adjacency row. Pass 1: tight (j,a) compaction scan (pure stream).
// Pass 2: leaky+exp+sum over ~60 compacted nonzeros (inputs ~0.1-scale => |e|<<1,
// softmax safe without max-subtraction). Pass 3: two sparse matvecs.
__global__ __launch_bounds__(256) void k_gat(const float* adj, const float* h,
                                             const float* wh1, const float* wh2,
                                             const int* used, float* gat, float* trans) {
    int row = blockIdx.x;
    if (!used[row]) return;
    __shared__ int s_j[MAXNZ];
    __shared__ float s_a[MAXNZ];
    __shared__ float s_e[MAXNZ];   // exp(e)
    __shared__ int s_cnt;
    __shared__ float s_part[4];
    __shared__ float s_g[4][64];
    __shared__ float s_t[4][64];
    int tid = threadIdx.x;
    if (tid == 0) s_cnt = 0;
    __syncthreads();
    const float* arow = adj + (size_t)row * NP1;

    // row byte alignment: (row*6001) % 4 == row % 4 elements
    int j0 = (4 - (row & 3)) & 3;
    int nv = (NP1 - j0) >> 2;

    for (int j = tid; j < j0; j += 256) {
        float a = arow[j];
        if (a > 0.f) {
            int pos = atomicAdd(&s_cnt, 1);
            if (pos < MAXNZ) { s_j[pos] = j; s_a[pos] = a; }
        }
    }
    const float4* av = (const float4*)(arow + j0);
    for (int v = tid; v < nv; v += 256) {
        float4 a4 = av[v];
        int jb = j0 + 4 * v;
        if (a4.x > 0.f) { int pos = atomicAdd(&s_cnt, 1); if (pos < MAXNZ) { s_j[pos] = jb;     s_a[pos] = a4.x; } }
        if (a4.y > 0.f) { int pos = atomicAdd(&s_cnt, 1); if (pos < MAXNZ) { s_j[pos] = jb + 1; s_a[pos] = a4.y; } }
        if (a4.z > 0.f) { int pos = atomicAdd(&s_cnt, 1); if (pos < MAXNZ) { s_j[pos] = jb + 2; s_a[pos] = a4.z; } }
        if (a4.w > 0.f) { int pos = atomicAdd(&s_cnt, 1); if (pos < MAXNZ) { s_j[pos] = jb + 3; s_a[pos] = a4.w; } }
    }
    for (int j = j0 + 4 * nv + tid; j < NP1; j += 256) {
        float a = arow[j];
        if (a > 0.f) {
            int pos = atomicAdd(&s_cnt, 1);
            if (pos < MAXNZ) { s_j[pos] = j; s_a[pos] = a; }
        }
    }
    __syncthreads();
    int cnt = min(s_cnt, MAXNZ);
    float w1 = wh1[row];
    float ssum = 0.f;
    for (int i = tid; i < cnt; i += 256) {
        float e = w1 + wh2[s_j[i]];
        e = e > 0.f ? e : 0.01f * e;
        float ee = __expf(e);
        s_e[i] = ee;
        ssum += ee;
    }
    int lane = tid & 63, g = tid >> 6;
    for (int o = 32; o > 0; o >>= 1) ssum += __shfl_xor(ssum, o, 64);
    if (lane == 0) s_part[g] = ssum;
    __syncthreads();
    float inv = __builtin_amdgcn_rcpf(s_part[0] + s_part[1] + s_part[2] + s_part[3]);
    float gacc = 0.f, tacc = 0.f;
    for (int i = g; i < cnt; i += 4) {
        int j = s_j[i];
        float hv = h[(size_t)j * 64 + lane];
        gacc += s_e[i] * hv;
        tacc += s_a[i] * hv;
    }
    s_g[g][lane] = gacc * inv;
    s_t[g][lane] = tacc;
    __syncthreads();
    if (g == 0) {
        gat[(size_t)row * 64 + lane]   = s_g[0][lane] + s_g[1][lane] + s_g[2][lane] + s_g[3][lane];
        trans[(size_t)row * 64 + lane] = s_t[0][lane] + s_t[1][lane] + s_t[2][lane] + s_t[3][lane];
    }
}

// seqs = coff*gat + (1-coff)*trans + self ; M1 = seqs_pos@W1 ; M2T[b][d][l] = (seqs_pos@W2)[d]
__global__ __launch_bounds__(256) void k_seq(const int* logs, const float* gat, const float* trans,
                                             const float* emb, const float* posemb,
                                             const float* cc_, const float* cn_,
                                             const float* W1_, const float* W2_,
                                             float* seqs, float* M1, float* M2T) {
    __shared__ float cc[4096], cn[4096], W1[4096], W2[4096];
    int tid = threadIdx.x;
    {
        float4* c4 = (float4*)cc; float4* n4 = (float4*)cn;
        float4* w14 = (float4*)W1; float4* w24 = (float4*)W2;
        const float4* sc = (const float4*)cc_; const float4* sn = (const float4*)cn_;
        const float4* s1 = (const float4*)W1_; const float4* s2 = (const float4*)W2_;
        for (int i = tid; i < 1024; i += 256) {
            c4[i] = sc[i]; n4[i] = sn[i]; w14[i] = s1[i]; w24[i] = s2[i];
        }
    }
    __syncthreads();
    int wave = tid >> 6, lane = tid & 63;
    for (int i = 0; i < 2; i++) {
        int p = blockIdx.x * 8 + wave * 2 + i;   // grid 800 -> 6400 positions
        int b = p / 200, l = p - b * 200;
        int n = logs[p];
        float g = gat[(size_t)n * 64 + lane];
        float t = trans[(size_t)n * 64 + lane];
        float se = emb[(size_t)n * 64 + lane];
        float ci = 0.f;
        #pragma unroll
        for (int k = 0; k < 64; k++) {
            float gk = __shfl(g, k, 64), tk = __shfl(t, k, 64);
            ci += gk * cc[k * 64 + lane] + tk * cn[k * 64 + lane];
        }
        float coff = 1.f / (1.f + __expf(-ci));
        float s = coff * g + (1.f - coff) * t + se;
        seqs[(size_t)p * 64 + lane] = s;
        float sp = s + (n != 0 ? posemb[l * 64 + lane] : 0.f);
        float m1 = 0.f, m2 = 0.f;
        #pragma unroll
        for (int k = 0; k < 64; k++) {
            float sk = __shfl(sp, k, 64);
            m1 += sk * W1[k * 64 + lane];
            m2 += sk * W2[k * 64 + lane];
        }
        M1[(size_t)p * 64 + lane] = m1;
        M2T[((size_t)b * 64 + lane) * 200 + l] = m2;
    }
}

// score[b,q,k] = sum_d sigmoid(M1[b,q,d]+M2[b,k,d]) * b_attn[d]; causal triples only.
__global__ __launch_bounds__(256) void k_score(const float* M1, const float* M2T,
                                               const float* battn, float* score) {
    __shared__ float bv[64];
    int tid = threadIdx.x;
    if (tid < 64) bv[tid] = battn[tid];
    __syncthreads();
    int idx = blockIdx.x * 256 + tid;          // grid 2513 -> 643,328 (need 643,200)
    if (idx >= TRI * 32) return;
    int b = idx / TRI;
    int t = idx - b * TRI;
    int q = (int)((sqrtf(8.0f * (float)t + 1.0f) - 1.0f) * 0.5f);
    while ((q + 1) * (q + 2) / 2 <= t) q++;
    while (q * (q + 1) / 2 > t) q--;
    int k = t - q * (q + 1) / 2;
    const float* m1 = M1 + ((size_t)(b * 200 + q)) * 64;
    const float* m2 = M2T + (size_t)b * 12800 + k;
    float s0 = 0.f, s1 = 0.f, s2 = 0.f, s3 = 0.f;
    #pragma unroll
    for (int d = 0; d < 64; d += 4) {
        float x0 = m1[d + 0] + m2[(size_t)(d + 0) * 200];
        float x1 = m1[d + 1] + m2[(size_t)(d + 1) * 200];
        float x2 = m1[d + 2] + m2[(size_t)(d + 2) * 200];
        float x3 = m1[d + 3] + m2[(size_t)(d + 3) * 200];
        s0 += bv[d + 0] * __builtin_amdgcn_rcpf(1.0f + __expf(-x0));
        s1 += bv[d + 1] * __builtin_amdgcn_rcpf(1.0f + __expf(-x1));
        s2 += bv[d + 2] * __builtin_amdgcn_rcpf(1.0f + __expf(-x2));
        s3 += bv[d + 3] * __builtin_amdgcn_rcpf(1.0f + __expf(-x3));
    }
    score[((size_t)(b * 200 + q)) * 200 + k] = (s0 + s1) + (s2 + s3);
}

// fused: final + FFN + UpDown + logits. Wave handles TWO consecutive q of the same b,
// sharing the seqs[b] k-loop loads for the overlapping range (halves L2 traffic).
__global__ __launch_bounds__(256) void k_finffn(const float* score, const float* seqs,
                                                const int* poss, const int* negs,
                                                const float* emb,
                                                const float* c1w, const float* c1b,
                                                const float* c2w, const float* c2b,
                                                const float* upw, const float* upb,
                                                const float* gw, const float* gb,
                                                const float* dw, const float* db,
                                                float* out) {
    __shared__ float wl[16384];   // c1w(4096) | c2w(4096) | dw(8192)
    int tid = threadIdx.x;
    {
        float4* l4 = (float4*)wl;
        const float4* a4 = (const float4*)c1w;
        const float4* b4 = (const float4*)c2w;
        const float4* d4 = (const float4*)dw;
        for (int i = tid; i < 1024; i += 256) l4[i] = a4[i];
        for (int i = tid; i < 1024; i += 256) l4[1024 + i] = b4[i];
        for (int i = tid; i < 2048; i += 256) l4[2048 + i] = d4[i];
    }
    __syncthreads();
    int wave = tid >> 6, lane = tid & 63;
    int pp = blockIdx.x * 4 + wave;         // grid 800 -> 3200 pairs
    int p0 = pp * 2;                        // q pair (p0, p0+1), same b always (200 even)
    int b = p0 / 200, q0 = p0 - b * 200;    // q1 = q0+1
    const float* srow0 = score + (size_t)p0 * 200;
    const float* srow1 = srow0 + 200;
    const float* sq = seqs + (size_t)b * 12800;

    // shared range k <= q0 for both q's; q1 additionally needs k = q0+1
    float a0 = 0.f, a1 = 0.f, a2 = 0.f, a3 = 0.f;   // acc for q0
    float c0 = 0.f, c1 = 0.f, c2 = 0.f, c3 = 0.f;   // acc for q1
    int k = 0;
    for (; k + 3 <= q0; k += 4) {
        float4 s4 = *(const float4*)(srow0 + k);
        float4 t4 = *(const float4*)(srow1 + k);
        float v0 = sq[(k + 0) * 64 + lane];
        float v1 = sq[(k + 1) * 64 + lane];
        float v2 = sq[(k + 2) * 64 + lane];
        float v3 = sq[(k + 3) * 64 + lane];
        a0 += s4.x * v0; c0 += t4.x * v0;
        a1 += s4.y * v1; c1 += t4.y * v1;
        a2 += s4.z * v2; c2 += t4.z * v2;
        a3 += s4.w * v3; c3 += t4.w * v3;
    }
    for (; k <= q0; k++) {
        float v = sq[k * 64 + lane];
        a0 += srow0[k] * v;
        c0 += srow1[k] * v;
    }
    c1 += srow1[q0 + 1] * sq[(q0 + 1) * 64 + lane];
    float x_q[2];
    x_q[0] = (a0 + a1) + (a2 + a3);
    x_q[1] = (c0 + c1) + (c2 + c3);

    #pragma unroll
    for (int qi = 0; qi < 2; qi++) {
        int p = p0 + qi;
        float x = x_q[qi];
        // ---- PointWiseFeedForward ----
        float acc = c1b[lane];
        #pragma unroll
        for (int kk = 0; kk < 64; kk++) acc += __shfl(x, kk, 64) * wl[kk * 64 + lane];
        float h1 = acc > 0.f ? acc : 0.f;
        acc = c2b[lane];
        #pragma unroll
        for (int kk = 0; kk < 64; kk++) acc += __shfl(h1, kk, 64) * wl[4096 + kk * 64 + lane];
        float x2 = x + acc;
        // ---- UpDown ----
        float u0 = upb[lane], u1 = upb[64 + lane];
        float g0 = gb[lane],  g1 = gb[64 + lane];
        #pragma unroll
        for (int kk = 0; kk < 64; kk++) {
            float xk = __shfl(x2, kk, 64);
            u0 += xk * upw[kk * 128 + lane];
            u1 += xk * upw[kk * 128 + 64 + lane];
            g0 += xk * gw[kk * 128 + lane];
            g1 += xk * gw[kk * 128 + 64 + lane];
        }
        g0 = g0 > 0.f ? g0 : 0.f;
        g1 = g1 > 0.f ? g1 : 0.f;
        float hh0 = g0 * u0, hh1 = g1 * u1;
        acc = db[lane];
        #pragma unroll
        for (int kk = 0; kk < 64; kk++) acc += __shfl(hh0, kk, 64) * wl[8192 + kk * 64 + lane];
        #pragma unroll
        for (int kk = 0; kk < 64; kk++) acc += __shfl(hh1, kk, 64) * wl[8192 + (64 + kk) * 64 + lane];
        float x3 = x2 + (acc > 0.f ? acc : 0.f);
        // ---- logits ----
        int pn = poss[p], nn = negs[p];
        float pl = x3 * emb[(size_t)pn * 64 + lane];
        float nl = x3 * emb[(size_t)nn * 64 + lane];
        for (int o = 32; o > 0; o >>= 1) {
            pl += __shfl_xor(pl, o, 64);
            nl += __shfl_xor(nl, o, 64);
        }
        if (lane == 0) { out[p] = pl; out[BLn + p] = nl; }
    }
}

extern "C" void kernel_launch(void* const* d_in, const int* in_sizes, int n_in,
                              void* d_out, int out_size, void* d_ws, size_t ws_size,
                              hipStream_t stream) {
    const int* logs = (const int*)d_in[0];
    const int* poss = (const int*)d_in[1];
    const int* negs = (const int*)d_in[2];
    const float* adj      = (const float*)d_in[4];
    const float* item_emb = (const float*)d_in[5];
    const float* posemb   = (const float*)d_in[6];
    const float* W_item   = (const float*)d_in[7];
    const float* a_item   = (const float*)d_in[8];
    const float* W_1      = (const float*)d_in[9];
    const float* W_2      = (const float*)d_in[10];
    const float* b_attn   = (const float*)d_in[11];
    const float* cc       = (const float*)d_in[12];
    const float* cn       = (const float*)d_in[13];
    const float* c1w      = (const float*)d_in[14];
    const float* c1b      = (const float*)d_in[15];
    const float* c2w      = (const float*)d_in[16];
    const float* c2b      = (const float*)d_in[17];
    const float* upw      = (const float*)d_in[18];
    const float* upb      = (const float*)d_in[19];
    const float* gw       = (const float*)d_in[20];
    const float* gb       = (const float*)d_in[21];
    const float* dw       = (const float*)d_in[22];
    const float* db       = (const float*)d_in[23];
    float* out = (float*)d_out;

    float* W = (float*)d_ws;
    size_t off = 0;
    float* h_item = W + off; off += 384064;   // 6001*64
    float* wh1    = W + off; off += 6016;
    float* wh2    = W + off; off += 6016;
    int*   used   = (int*)(W + off); off += 6016;
    float* gat    = W + off; off += 384064;
    float* trans  = W + off; off += 384064;
    float* seqs   = W + off; off += 409600;   // 6400*64
    float* M1     = W + off; off += 409600;
    float* M2T    = W + off; off += 409600;   // [32][64][200]
    float* score  = W + off; off += 1280000;  // [32][200][200]

    k_hitem <<<1501, 256, 0, stream>>>(item_emb, W_item, a_item, h_item, wh1, wh2, used);
    k_mark  <<<25, 256, 0, stream>>>(logs, used);
    k_gat   <<<6001, 256, 0, stream>>>(adj, h_item, wh1, wh2, used, gat, trans);
    k_seq   <<<800, 256, 0, stream>>>(logs, gat, trans, item_emb, posemb, cc, cn, W_1, W_2,
                                      seqs, M1, M2T);
    k_score <<<2513, 256, 0, stream>>>(M1, M2T, b_attn, score);
    k_finffn<<<800, 256, 0, stream>>>(score, seqs, poss, negs, item_emb,
                                      c1w, c1b, c2w, c2b, upw, upb, gw, gb, dw, db, out);
}

// Round 7
// 411.580 us; speedup vs baseline: 1.2244x; 1.2244x over previous
//
#include <hip/hip_runtime.h>
#include <hip/hip_bf16.h>
#include <cstddef>

#define NP1 6001
#define BLn 6400
#define TRI 20100   // 200*201/2 causal pairs per batch

__global__ __launch_bounds__(256) void k_mark(const int* logs, int* used) {
    int i = blockIdx.x * 256 + threadIdx.x;
    if (i < BLn) used[logs[i]] = 1;
}

// used=0 init folded in; h_item = item_emb @ W_item ; wh1 = h@a[:64] ; wh2 = h@a[64:]
__global__ __launch_bounds__(256) void k_hitem(const float* emb, const float* Wi,
                                               const float* a_item,
                                               float* h, float* wh1, float* wh2, int* used) {
    __shared__ float Wl[4096];
    int tid = threadIdx.x;
    int gid = blockIdx.x * 256 + tid;
    if (gid < NP1) used[gid] = 0;
    {
        const float4* w4 = (const float4*)Wi;
        float4* l4 = (float4*)Wl;
        for (int i = tid; i < 1024; i += 256) l4[i] = w4[i];
    }
    __syncthreads();
    int wave = tid >> 6, lane = tid & 63;
    int row = blockIdx.x * 4 + wave;
    if (row >= NP1) return;
    float e = emb[(size_t)row * 64 + lane];
    float acc = 0.f;
    #pragma unroll
    for (int k = 0; k < 64; k++) acc += __shfl(e, k, 64) * Wl[k * 64 + lane];
    h[(size_t)row * 64 + lane] = acc;
    float p1 = acc * a_item[lane];
    float p2 = acc * a_item[64 + lane];
    for (int off = 32; off > 0; off >>= 1) {
        p1 += __shfl_down(p1, off, 64);
        p2 += __shfl_down(p2, off, 64);
    }
    if (lane == 0) { wh1[row] = p1; wh2[row] = p2; }
}

#define MAXNZ 1024
// one block per adjacency row. Pass 1: tight (j,a) compaction scan (pure stream).
// Pass 2: leaky+exp+sum over ~60 compacted nonzeros (inputs ~0.1-scale => |e|<<1,
// softmax safe without max-subtraction). Pass 3: two sparse matvecs.
__global__ __launch_bounds__(256) void k_gat(const float* adj, const float* h,
                                             const float* wh1, const float* wh2,
                                             const int* used, float* gat, float* trans) {
    int row = blockIdx.x;
    if (!used[row]) return;
    __shared__ int s_j[MAXNZ];
    __shared__ float s_a[MAXNZ];
    __shared__ float s_e[MAXNZ];   // exp(e)
    __shared__ int s_cnt;
    __shared__ float s_part[4];
    __shared__ float s_g[4][64];
    __shared__ float s_t[4][64];
    int tid = threadIdx.x;
    if (tid == 0) s_cnt = 0;
    __syncthreads();
    const float* arow = adj + (size_t)row * NP1;

    // row byte alignment: (row*6001) % 4 == row % 4 elements
    int j0 = (4 - (row & 3)) & 3;
    int nv = (NP1 - j0) >> 2;

    for (int j = tid; j < j0; j += 256) {
        float a = arow[j];
        if (a > 0.f) {
            int pos = atomicAdd(&s_cnt, 1);
            if (pos < MAXNZ) { s_j[pos] = j; s_a[pos] = a; }
        }
    }
    const float4* av = (const float4*)(arow + j0);
    for (int v = tid; v < nv; v += 256) {
        float4 a4 = av[v];
        int jb = j0 + 4 * v;
        if (a4.x > 0.f) { int pos = atomicAdd(&s_cnt, 1); if (pos < MAXNZ) { s_j[pos] = jb;     s_a[pos] = a4.x; } }
        if (a4.y > 0.f) { int pos = atomicAdd(&s_cnt, 1); if (pos < MAXNZ) { s_j[pos] = jb + 1; s_a[pos] = a4.y; } }
        if (a4.z > 0.f) { int pos = atomicAdd(&s_cnt, 1); if (pos < MAXNZ) { s_j[pos] = jb + 2; s_a[pos] = a4.z; } }
        if (a4.w > 0.f) { int pos = atomicAdd(&s_cnt, 1); if (pos < MAXNZ) { s_j[pos] = jb + 3; s_a[pos] = a4.w; } }
    }
    for (int j = j0 + 4 * nv + tid; j < NP1; j += 256) {
        float a = arow[j];
        if (a > 0.f) {
            int pos = atomicAdd(&s_cnt, 1);
            if (pos < MAXNZ) { s_j[pos] = j; s_a[pos] = a; }
        }
    }
    __syncthreads();
    int cnt = min(s_cnt, MAXNZ);
    float w1 = wh1[row];
    float ssum = 0.f;
    for (int i = tid; i < cnt; i += 256) {
        float e = w1 + wh2[s_j[i]];
        e = e > 0.f ? e : 0.01f * e;
        float ee = __expf(e);
        s_e[i] = ee;
        ssum += ee;
    }
    int lane = tid & 63, g = tid >> 6;
    for (int o = 32; o > 0; o >>= 1) ssum += __shfl_xor(ssum, o, 64);
    if (lane == 0) s_part[g] = ssum;
    __syncthreads();
    float inv = __builtin_amdgcn_rcpf(s_part[0] + s_part[1] + s_part[2] + s_part[3]);
    float gacc = 0.f, tacc = 0.f;
    for (int i = g; i < cnt; i += 4) {
        int j = s_j[i];
        float hv = h[(size_t)j * 64 + lane];
        gacc += s_e[i] * hv;
        tacc += s_a[i] * hv;
    }
    s_g[g][lane] = gacc * inv;
    s_t[g][lane] = tacc;
    __syncthreads();
    if (g == 0) {
        gat[(size_t)row * 64 + lane]   = s_g[0][lane] + s_g[1][lane] + s_g[2][lane] + s_g[3][lane];
        trans[(size_t)row * 64 + lane] = s_t[0][lane] + s_t[1][lane] + s_t[2][lane] + s_t[3][lane];
    }
}

// seqs = coff*gat + (1-coff)*trans + self ; M1 = seqs_pos@W1 ; M2T[b][d][l] = (seqs_pos@W2)[d]
__global__ __launch_bounds__(256) void k_seq(const int* logs, const float* gat, const float* trans,
                                             const float* emb, const float* posemb,
                                             const float* cc_, const float* cn_,
                                             const float* W1_, const float* W2_,
                                             float* seqs, float* M1, float* M2T) {
    __shared__ float cc[4096], cn[4096], W1[4096], W2[4096];
    int tid = threadIdx.x;
    {
        float4* c4 = (float4*)cc; float4* n4 = (float4*)cn;
        float4* w14 = (float4*)W1; float4* w24 = (float4*)W2;
        const float4* sc = (const float4*)cc_; const float4* sn = (const float4*)cn_;
        const float4* s1 = (const float4*)W1_; const float4* s2 = (const float4*)W2_;
        for (int i = tid; i < 1024; i += 256) {
            c4[i] = sc[i]; n4[i] = sn[i]; w14[i] = s1[i]; w24[i] = s2[i];
        }
    }
    __syncthreads();
    int wave = tid >> 6, lane = tid & 63;
    for (int i = 0; i < 2; i++) {
        int p = blockIdx.x * 8 + wave * 2 + i;   // grid 800 -> 6400 positions
        int b = p / 200, l = p - b * 200;
        int n = logs[p];
        float g = gat[(size_t)n * 64 + lane];
        float t = trans[(size_t)n * 64 + lane];
        float se = emb[(size_t)n * 64 + lane];
        float ci = 0.f;
        #pragma unroll
        for (int k = 0; k < 64; k++) {
            float gk = __shfl(g, k, 64), tk = __shfl(t, k, 64);
            ci += gk * cc[k * 64 + lane] + tk * cn[k * 64 + lane];
        }
        float coff = 1.f / (1.f + __expf(-ci));
        float s = coff * g + (1.f - coff) * t + se;
        seqs[(size_t)p * 64 + lane] = s;
        float sp = s + (n != 0 ? posemb[l * 64 + lane] : 0.f);
        float m1 = 0.f, m2 = 0.f;
        #pragma unroll
        for (int k = 0; k < 64; k++) {
            float sk = __shfl(sp, k, 64);
            m1 += sk * W1[k * 64 + lane];
            m2 += sk * W2[k * 64 + lane];
        }
        M1[(size_t)p * 64 + lane] = m1;
        M2T[((size_t)b * 64 + lane) * 200 + l] = m2;
    }
}

// score[b,q,k] = sum_d sigmoid(M1[b,q,d]+M2[b,k,d]) * b_attn[d]; causal triples only.
__global__ __launch_bounds__(256) void k_score(const float* M1, const float* M2T,
                                               const float* battn, float* score) {
    __shared__ float bv[64];
    int tid = threadIdx.x;
    if (tid < 64) bv[tid] = battn[tid];
    __syncthreads();
    int idx = blockIdx.x * 256 + tid;          // grid 2513 -> 643,328 (need 643,200)
    if (idx >= TRI * 32) return;
    int b = idx / TRI;
    int t = idx - b * TRI;
    int q = (int)((sqrtf(8.0f * (float)t + 1.0f) - 1.0f) * 0.5f);
    while ((q + 1) * (q + 2) / 2 <= t) q++;
    while (q * (q + 1) / 2 > t) q--;
    int k = t - q * (q + 1) / 2;
    const float* m1 = M1 + ((size_t)(b * 200 + q)) * 64;
    const float* m2 = M2T + (size_t)b * 12800 + k;
    float s0 = 0.f, s1 = 0.f, s2 = 0.f, s3 = 0.f;
    #pragma unroll
    for (int d = 0; d < 64; d += 4) {
        float x0 = m1[d + 0] + m2[(size_t)(d + 0) * 200];
        float x1 = m1[d + 1] + m2[(size_t)(d + 1) * 200];
        float x2 = m1[d + 2] + m2[(size_t)(d + 2) * 200];
        float x3 = m1[d + 3] + m2[(size_t)(d + 3) * 200];
        s0 += bv[d + 0] * __builtin_amdgcn_rcpf(1.0f + __expf(-x0));
        s1 += bv[d + 1] * __builtin_amdgcn_rcpf(1.0f + __expf(-x1));
        s2 += bv[d + 2] * __builtin_amdgcn_rcpf(1.0f + __expf(-x2));
        s3 += bv[d + 3] * __builtin_amdgcn_rcpf(1.0f + __expf(-x3));
    }
    score[((size_t)(b * 200 + q)) * 200 + k] = (s0 + s1) + (s2 + s3);
}

// fused: final[b,q,:] = sum_{k<=q} score*seqs, then FFN + UpDown + logits; wave per position
// NOTE (R6 lesson): do NOT pair two q per wave here — doubling live accumulator state
// pushed VGPR_Count to 256 and spilled to scratch (WRITE_SIZE 66 MB), 215 us regression.
__global__ __launch_bounds__(256) void k_finffn(const float* score, const float* seqs,
                                                const int* poss, const int* negs,
                                                const float* emb,
                                                const float* c1w, const float* c1b,
                                                const float* c2w, const float* c2b,
                                                const float* upw, const float* upb,
                                                const float* gw, const float* gb,
                                                const float* dw, const float* db,
                                                float* out) {
    __shared__ float wl[16384];   // c1w(4096) | c2w(4096) | dw(8192)
    int tid = threadIdx.x;
    {
        float4* l4 = (float4*)wl;
        const float4* a4 = (const float4*)c1w;
        const float4* b4 = (const float4*)c2w;
        const float4* d4 = (const float4*)dw;
        for (int i = tid; i < 1024; i += 256) l4[i] = a4[i];
        for (int i = tid; i < 1024; i += 256) l4[1024 + i] = b4[i];
        for (int i = tid; i < 2048; i += 256) l4[2048 + i] = d4[i];
    }
    __syncthreads();
    int wave = tid >> 6, lane = tid & 63;
    int p = blockIdx.x * 4 + wave;          // grid 1600 -> 6400
    int b = p / 200, q = p - b * 200;

    // ---- final = score_row @ seqs[b] ----
    const float* srow = score + (size_t)p * 200;
    const float* sq = seqs + (size_t)b * 12800;
    float a0 = 0.f, a1 = 0.f, a2 = 0.f, a3 = 0.f;
    int k = 0;
    #pragma unroll 2
    for (; k + 3 <= q; k += 4) {
        float4 s4 = *(const float4*)(srow + k);
        a0 += s4.x * sq[(k + 0) * 64 + lane];
        a1 += s4.y * sq[(k + 1) * 64 + lane];
        a2 += s4.z * sq[(k + 2) * 64 + lane];
        a3 += s4.w * sq[(k + 3) * 64 + lane];
    }
    for (; k <= q; k++) a0 += srow[k] * sq[k * 64 + lane];
    float x = (a0 + a1) + (a2 + a3);

    // ---- PointWiseFeedForward ----
    float acc = c1b[lane];
    #pragma unroll
    for (int kk = 0; kk < 64; kk++) acc += __shfl(x, kk, 64) * wl[kk * 64 + lane];
    float h1 = acc > 0.f ? acc : 0.f;
    acc = c2b[lane];
    #pragma unroll
    for (int kk = 0; kk < 64; kk++) acc += __shfl(h1, kk, 64) * wl[4096 + kk * 64 + lane];
    float x2 = x + acc;
    // ---- UpDown ----
    float u0 = upb[lane], u1 = upb[64 + lane];
    float g0 = gb[lane],  g1 = gb[64 + lane];
    #pragma unroll
    for (int kk = 0; kk < 64; kk++) {
        float xk = __shfl(x2, kk, 64);
        u0 += xk * upw[kk * 128 + lane];
        u1 += xk * upw[kk * 128 + 64 + lane];
        g0 += xk * gw[kk * 128 + lane];
        g1 += xk * gw[kk * 128 + 64 + lane];
    }
    g0 = g0 > 0.f ? g0 : 0.f;
    g1 = g1 > 0.f ? g1 : 0.f;
    float hh0 = g0 * u0, hh1 = g1 * u1;
    acc = db[lane];
    #pragma unroll
    for (int kk = 0; kk < 64; kk++) acc += __shfl(hh0, kk, 64) * wl[8192 + kk * 64 + lane];
    #pragma unroll
    for (int kk = 0; kk < 64; kk++) acc += __shfl(hh1, kk, 64) * wl[8192 + (64 + kk) * 64 + lane];
    float x3 = x2 + (acc > 0.f ? acc : 0.f);
    // ---- logits ----
    int pn = poss[p], nn = negs[p];
    float pl = x3 * emb[(size_t)pn * 64 + lane];
    float nl = x3 * emb[(size_t)nn * 64 + lane];
    for (int o = 32; o > 0; o >>= 1) {
        pl += __shfl_xor(pl, o, 64);
        nl += __shfl_xor(nl, o, 64);
    }
    if (lane == 0) { out[p] = pl; out[BLn + p] = nl; }
}

extern "C" void kernel_launch(void* const* d_in, const int* in_sizes, int n_in,
                              void* d_out, int out_size, void* d_ws, size_t ws_size,
                              hipStream_t stream) {
    const int* logs = (const int*)d_in[0];
    const int* poss = (const int*)d_in[1];
    const int* negs = (const int*)d_in[2];
    const float* adj      = (const float*)d_in[4];
    const float* item_emb = (const float*)d_in[5];
    const float* posemb   = (const float*)d_in[6];
    const float* W_item   = (const float*)d_in[7];
    const float* a_item   = (const float*)d_in[8];
    const float* W_1      = (const float*)d_in[9];
    const float* W_2      = (const float*)d_in[10];
    const float* b_attn   = (const float*)d_in[11];
    const float* cc       = (const float*)d_in[12];
    const float* cn       = (const float*)d_in[13];
    const float* c1w      = (const float*)d_in[14];
    const float* c1b      = (const float*)d_in[15];
    const float* c2w      = (const float*)d_in[16];
    const float* c2b      = (const float*)d_in[17];
    const float* upw      = (const float*)d_in[18];
    const float* upb      = (const float*)d_in[19];
    const float* gw       = (const float*)d_in[20];
    const float* gb       = (const float*)d_in[21];
    const float* dw       = (const float*)d_in[22];
    const float* db       = (const float*)d_in[23];
    float* out = (float*)d_out;

    float* W = (float*)d_ws;
    size_t off = 0;
    float* h_item = W + off; off += 384064;   // 6001*64
    float* wh1    = W + off; off += 6016;
    float* wh2    = W + off; off += 6016;
    int*   used   = (int*)(W + off); off += 6016;
    float* gat    = W + off; off += 384064;
    float* trans  = W + off; off += 384064;
    float* seqs   = W + off; off += 409600;   // 6400*64
    float* M1     = W + off; off += 409600;
    float* M2T    = W + off; off += 409600;   // [32][64][200]
    float* score  = W + off; off += 1280000;  // [32][200][200]

    k_hitem <<<1501, 256, 0, stream>>>(item_emb, W_item, a_item, h_item, wh1, wh2, used);
    k_mark  <<<25, 256, 0, stream>>>(logs, used);
    k_gat   <<<6001, 256, 0, stream>>>(adj, h_item, wh1, wh2, used, gat, trans);
    k_seq   <<<800, 256, 0, stream>>>(logs, gat, trans, item_emb, posemb, cc, cn, W_1, W_2,
                                      seqs, M1, M2T);
    k_score <<<2513, 256, 0, stream>>>(M1, M2T, b_attn, score);
    k_finffn<<<1600, 256, 0, stream>>>(score, seqs, poss, negs, item_emb,
                                       c1w, c1b, c2w, c2b, upw, upb, gw, gb, dw, db, out);
}